// Round 10
// baseline (270.248 us; speedup 1.0000x reference)
//
#include <hip/hip_runtime.h>
#include <hip/hip_bf16.h>
#include <math.h>

typedef __bf16 bf16x8 __attribute__((ext_vector_type(8)));
typedef __bf16 bf16x2 __attribute__((ext_vector_type(2)));
typedef short  s16x2  __attribute__((ext_vector_type(2)));
typedef short  s16x4  __attribute__((ext_vector_type(4)));
typedef float  floatx16 __attribute__((ext_vector_type(16)));

// Workspace layout (bytes):
//   Kq   bf16 [2][8192][16]   offset 0        (512 KB)  scaled by sqrt(log2 e)
//   Vswz bf16 [2][8192][32]   offset 524288   (1 MB)    B-frag swizzled order
//   Oacc f32  [2*8192][32]    offset 1572864  (2 MB)    atomic accumulator
//   Lacc f32  [2*8192]        offset 3669888  (64 KB)
//   Cnt  i32  [2*64]          offset 3735552  (512 B)   per-(b,itile) finish counter
#define KQ_ELEMS (2 * 8192 * 16)
#define OACC_OFF 1572864
#define SQRT_LOG2E 1.2011224087864498f
#define LSPLIT 4

// ---------------- Kernel A: zero accumulators + projections ----------------
__global__ __launch_bounds__(256) void proj_kernel(
    const float* __restrict__ in, const float* __restrict__ W1,
    const float* __restrict__ b1, const float* __restrict__ W2,
    const float* __restrict__ b2,
    __hip_bfloat16* __restrict__ Kq, __hip_bfloat16* __restrict__ Vswz,
    float* __restrict__ acc0)
{
    __shared__ float Xs[32][32];
    __shared__ float W1s[16 * 32];
    __shared__ float W2s[32 * 32];
    const int t = threadIdx.x;
    const int bid = blockIdx.x;       // 0..511
    const int b = bid >> 8;
    const int hw = bid & 255;

    // zero accumulators: Oacc 524288 f + Lacc 16384 f + Cnt 128 i32 (pad to 256 f)
    {
        int gid = bid * 256 + t;                       // 0..131071
        *(float4*)(acc0 + (size_t)gid * 4) = make_float4(0.f, 0.f, 0.f, 0.f);
        if (gid < 4160)
            *(float4*)(acc0 + 524288 + (size_t)gid * 4) = make_float4(0.f, 0.f, 0.f, 0.f);
    }

    {
        int l = t >> 3, cs = (t & 7) * 4;
        float4 v = *(const float4*)(in + (((size_t)b * 32 + l) * 256 + hw) * 32 + cs);
        *(float4*)&Xs[l][cs] = v;
    }
    if (t < 128) *(float4*)&W1s[t * 4] = *(const float4*)(W1 + t * 4);
    *(float4*)&W2s[t * 4] = *(const float4*)(W2 + t * 4);
    __syncthreads();

    const int c = t & 31;
    const int g = t >> 5;             // 0..7

#pragma unroll
    for (int oo = 0; oo < 2; ++oo) {
        int o = g * 2 + oo;           // 0..15
        float acc = b1[o];
#pragma unroll
        for (int l = 0; l < 32; ++l) acc += W1s[o * 32 + l] * Xs[l][c];
        int k = c >> 1;
        int i = (c & 1) * 4096 + o * 256 + hw;
        Kq[((size_t)b * 8192 + i) * 16 + k] = __float2bfloat16(acc * SQRT_LOG2E);
    }
#pragma unroll
    for (int oo = 0; oo < 4; ++oo) {
        int o = g * 4 + oo;           // 0..31
        float acc = b2[o];
#pragma unroll
        for (int l = 0; l < 32; ++l) acc += W2s[o * 32 + l] * Xs[l][c];
        // position j = o*256 + hw, channel c; B-frag swizzle:
        // flat = jt*1024 + gg*256 + h*128 + c*4 + idx
        int j = o * 256 + hw;
        int jt = j >> 5, rem = j & 31;
        int gg = rem >> 3, h = (rem >> 2) & 1, idx = rem & 3;
        Vswz[(size_t)b * 262144 + jt * 1024 + gg * 256 + h * 128 + c * 4 + idx] =
            __float2bfloat16(acc);
    }
}

// ---------------- Kernel B: flash attention + fused last-block epilogue ----------------
// block = 256 thr (4 waves), each wave owns 32 i-rows. grid = 2 * 64 * 16 = 2048.
// NOTE: no min-waves arg in __launch_bounds__ — forcing 8 waves/EU capped VGPR
// at 32 and spilled the accumulators to scratch (R7: +65 MB HBM traffic, 2x dur).
__global__ __launch_bounds__(256) void flash_kernel(
    const __hip_bfloat16* __restrict__ Kq, const __hip_bfloat16* __restrict__ Vswz,
    float* __restrict__ Oacc, float* __restrict__ Lacc, int* __restrict__ Cnt,
    const float* __restrict__ in, const float* __restrict__ gamma,
    float* __restrict__ out)
{
    const int t = threadIdx.x;
    const int lane = t & 63;
    const int wv = t >> 6;            // 0..3
    const int m = lane & 31;
    const int h = lane >> 5;          // 0/1

    const int bid = blockIdx.x;
    const int s = bid & ((1 << LSPLIT) - 1);
    const int itile = (bid >> LSPLIT) & 63;
    const int b = bid >> (LSPLIT + 6);
    const int i0 = itile * 128 + wv * 32;
    const int niter = (8192 >> LSPLIT) >> 5;   // 16 tiles of 32 j
    const int jt0 = s * niter;

    const __hip_bfloat16* Kb = Kq + (size_t)b * 8192 * 16;
    const __hip_bfloat16* Vb = Vswz + (size_t)b * 262144 + h * 128 + m * 4;

    // Q B-frag (regs): B[k=8h+idx][n=m] = Kq[i0+m][8h+idx]
    const bf16x8 bq = *(const bf16x8*)(Kb + (size_t)(i0 + m) * 16 + h * 8);

    floatx16 oa = {}, ob = {};
    float2 l01 = {0.f, 0.f}, l23 = {0.f, 0.f};

    // prefetch it = 0
    bf16x8 ak = *(const bf16x8*)(Kb + (size_t)(jt0 * 32 + m) * 16 + h * 8);
    s16x4 vf0 = *(const s16x4*)(Vb + (size_t)jt0 * 1024 + 0);
    s16x4 vf1 = *(const s16x4*)(Vb + (size_t)jt0 * 1024 + 256);
    s16x4 vf2 = *(const s16x4*)(Vb + (size_t)jt0 * 1024 + 512);
    s16x4 vf3 = *(const s16x4*)(Vb + (size_t)jt0 * 1024 + 768);

    for (int it = 0; it < niter; ++it) {
        const int jtn = jt0 + (it + 1 < niter ? it + 1 : it);
        bf16x8 ak_n = *(const bf16x8*)(Kb + (size_t)(jtn * 32 + m) * 16 + h * 8);
        s16x4 vn0 = *(const s16x4*)(Vb + (size_t)jtn * 1024 + 0);
        s16x4 vn1 = *(const s16x4*)(Vb + (size_t)jtn * 1024 + 256);
        s16x4 vn2 = *(const s16x4*)(Vb + (size_t)jtn * 1024 + 512);
        s16x4 vn3 = *(const s16x4*)(Vb + (size_t)jtn * 1024 + 768);

        // S^T(32j x 32i) = K(A) x Q(B), K=16 exact
        floatx16 sc = __builtin_amdgcn_mfma_f32_32x32x16_bf16(ak, bq, (floatx16){}, 0, 0, 0);

        // P = 2^S ; reg 4g+idx holds j_loc = 8g+4h+idx == 32x32x8 A-layout.
#pragma unroll
        for (int g = 0; g < 4; ++g) {
            float e0 = __builtin_amdgcn_exp2f(sc[4 * g + 0]);
            float e1 = __builtin_amdgcn_exp2f(sc[4 * g + 1]);
            float e2 = __builtin_amdgcn_exp2f(sc[4 * g + 2]);
            float e3 = __builtin_amdgcn_exp2f(sc[4 * g + 3]);
            l01.x += e0; l01.y += e1; l23.x += e2; l23.y += e3;
#if defined(__has_builtin) && __has_builtin(__builtin_amdgcn_cvt_pk_bf16_f32)
            bf16x2 plo = __builtin_amdgcn_cvt_pk_bf16_f32(e0, e1);
            bf16x2 phi = __builtin_amdgcn_cvt_pk_bf16_f32(e2, e3);
#else
            bf16x2 plo = {(__bf16)e0, (__bf16)e1};
            bf16x2 phi = {(__bf16)e2, (__bf16)e3};
#endif
            s16x2 lo = __builtin_bit_cast(s16x2, plo);
            s16x2 hi = __builtin_bit_cast(s16x2, phi);
            s16x4 pb = {lo[0], lo[1], hi[0], hi[1]};
            s16x4 vf = (g == 0) ? vf0 : (g == 1) ? vf1 : (g == 2) ? vf2 : vf3;
            if (g < 2)
                oa = __builtin_amdgcn_mfma_f32_32x32x8bf16_1k(pb, vf, oa, 0, 0, 0);
            else
                ob = __builtin_amdgcn_mfma_f32_32x32x8bf16_1k(pb, vf, ob, 0, 0, 0);
        }
        ak = ak_n; vf0 = vn0; vf1 = vn1; vf2 = vn2; vf3 = vn3;
    }

    oa = oa + ob;
    float l = (l01.x + l01.y) + (l23.x + l23.y);
    l += __shfl_xor(l, 32);

    // atomic-accumulate partials (plain sums: no max-rescaling in this scheme)
    // reg r -> row i_loc=(r&3)+8*(r>>2)+4h, col c=m
#pragma unroll
    for (int r = 0; r < 16; ++r) {
        int iloc = (r & 3) + 8 * (r >> 2) + 4 * h;
        size_t row = (size_t)b * 8192 + i0 + iloc;
        unsafeAtomicAdd(&Oacc[row * 32 + m], oa[r]);
    }
    if (h == 0)
        unsafeAtomicAdd(&Lacc[(size_t)b * 8192 + i0 + m], l);

    // ---- fused epilogue: last of the 16 split-blocks normalizes this i-tile ----
    __threadfence();      // my atomics are at L2 before the counter bump
    __syncthreads();      // ALL waves of this block have passed their fence
    __shared__ int sflag;
    if (t == 0) sflag = atomicAdd(&Cnt[b * 64 + itile], 1);
    __syncthreads();
    if (sflag == (1 << LSPLIT) - 1) {
        const float gm = gamma[0];
        const size_t rbase = (size_t)b * 8192 + itile * 128;   // 128 rows
        const size_t fbase = rbase * 32;                       // 4096 floats
        for (int e = t; e < 4096; e += 256) {
            // agent-scope loads bypass L1 (stale lines possible from a previous
            // graph replay's finisher on this CU — G16)
            float ov = __hip_atomic_load(&Oacc[fbase + e], __ATOMIC_RELAXED,
                                         __HIP_MEMORY_SCOPE_AGENT);
            float lv = __hip_atomic_load(&Lacc[rbase + (e >> 5)], __ATOMIC_RELAXED,
                                         __HIP_MEMORY_SCOPE_AGENT);
            out[fbase + e] = (ov / lv) * gm + in[fbase + e];
        }
    }
}

extern "C" void kernel_launch(void* const* d_in, const int* in_sizes, int n_in,
                              void* d_out, int out_size, void* d_ws, size_t ws_size,
                              hipStream_t stream) {
    const float* in = (const float*)d_in[0];
    const float* W1 = (const float*)d_in[1];
    const float* b1 = (const float*)d_in[2];
    const float* W2 = (const float*)d_in[3];
    const float* b2 = (const float*)d_in[4];
    const float* gamma = (const float*)d_in[5];
    float* out = (float*)d_out;

    __hip_bfloat16* Kq = (__hip_bfloat16*)d_ws;
    __hip_bfloat16* Vswz = Kq + KQ_ELEMS;
    float* Oacc = (float*)((char*)d_ws + OACC_OFF);
    float* Lacc = Oacc + 16384 * 32;
    int* Cnt = (int*)(Lacc + 16384);

    proj_kernel<<<512, 256, 0, stream>>>(in, W1, b1, W2, b2, Kq, Vswz, Oacc);
    flash_kernel<<<2 * 64 * (1 << LSPLIT), 256, 0, stream>>>(Kq, Vswz, Oacc, Lacc, Cnt,
                                                             in, gamma, out);
}

// Round 11
// 127.120 us; speedup vs baseline: 2.1259x; 2.1259x over previous
//
#include <hip/hip_runtime.h>
#include <hip/hip_bf16.h>
#include <math.h>

typedef __bf16 bf16x2 __attribute__((ext_vector_type(2)));
typedef short  s16x2  __attribute__((ext_vector_type(2)));
typedef short  s16x4  __attribute__((ext_vector_type(4)));
typedef float  floatx4 __attribute__((ext_vector_type(4)));

// Workspace layout (bytes):
//   Kq   bf16 [2][8192][16]   offset 0        (512 KB)  scaled by sqrt(log2 e)
//   Vswz bf16 [2][8192][32]   offset 524288   (1 MB)    16x16x16 B-frag swizzled
//   Oacc f32  [2*8192][32]    offset 1572864  (2 MB)    atomic accumulator
//   Lacc f32  [2*8192]        offset 3669888  (64 KB)
#define KQ_ELEMS (2 * 8192 * 16)
#define OACC_OFF 1572864
#define SQRT_LOG2E 1.2011224087864498f
#define LSPLIT 3

// ---------------- Kernel A: zero accumulators + projections ----------------
__global__ __launch_bounds__(256) void proj_kernel(
    const float* __restrict__ in, const float* __restrict__ W1,
    const float* __restrict__ b1, const float* __restrict__ W2,
    const float* __restrict__ b2,
    __hip_bfloat16* __restrict__ Kq, __hip_bfloat16* __restrict__ Vswz,
    float* __restrict__ acc0)
{
    __shared__ float Xs[32][32];
    __shared__ float W1s[16 * 32];
    __shared__ float W2s[32 * 32];
    const int t = threadIdx.x;
    const int bid = blockIdx.x;       // 0..511
    const int b = bid >> 8;
    const int hw = bid & 255;

    // zero accumulators: Oacc 524288 floats + Lacc 16384 floats
    {
        int gid = bid * 256 + t;                       // 0..131071
        *(float4*)(acc0 + (size_t)gid * 4) = make_float4(0.f, 0.f, 0.f, 0.f);
        if (gid < 4096)
            *(float4*)(acc0 + 524288 + (size_t)gid * 4) = make_float4(0.f, 0.f, 0.f, 0.f);
    }

    {
        int l = t >> 3, cs = (t & 7) * 4;
        float4 v = *(const float4*)(in + (((size_t)b * 32 + l) * 256 + hw) * 32 + cs);
        *(float4*)&Xs[l][cs] = v;
    }
    if (t < 128) *(float4*)&W1s[t * 4] = *(const float4*)(W1 + t * 4);
    *(float4*)&W2s[t * 4] = *(const float4*)(W2 + t * 4);
    __syncthreads();

    const int c = t & 31;
    const int g = t >> 5;             // 0..7

#pragma unroll
    for (int oo = 0; oo < 2; ++oo) {
        int o = g * 2 + oo;           // 0..15
        float acc = b1[o];
#pragma unroll
        for (int l = 0; l < 32; ++l) acc += W1s[o * 32 + l] * Xs[l][c];
        int k = c >> 1;
        int i = (c & 1) * 4096 + o * 256 + hw;
        Kq[((size_t)b * 8192 + i) * 16 + k] = __float2bfloat16(acc * SQRT_LOG2E);
    }
#pragma unroll
    for (int oo = 0; oo < 4; ++oo) {
        int o = g * 4 + oo;           // 0..31
        float acc = b2[o];
#pragma unroll
        for (int l = 0; l < 32; ++l) acc += W2s[o * 32 + l] * Xs[l][c];
        // position j = o*256 + hw, channel c.
        // 16x16x16 B-frag swizzle: elem = jt*512 + (c>>4)*256 + q*64 + (c&15)*4 + idx
        // where jt=j>>4, q=(j>>2)&3, idx=j&3
        int j = o * 256 + hw;
        int jt = j >> 4, q = (j >> 2) & 3, idx = j & 3;
        Vswz[(size_t)b * 262144 + jt * 512 + (c >> 4) * 256 + q * 64 + (c & 15) * 4 + idx] =
            __float2bfloat16(acc);
    }
}

// ---------------- Kernel B: flash attention, 16x16 tiles, 8 waves/SIMD ----------------
// block = 256 thr (4 waves), each wave owns 16 i-rows. grid = 2 * 128 * 8 = 2048.
// NOTE: no min-waves arg in __launch_bounds__ (R7: forcing 8/EU capped VGPR=32 -> spill).
// 16x16 tiles keep total regs (incl. accumulators) ~48 -> 8 waves/SIMD naturally.
__global__ __launch_bounds__(256) void flash_kernel(
    const __hip_bfloat16* __restrict__ Kq, const __hip_bfloat16* __restrict__ Vswz,
    float* __restrict__ Oacc, float* __restrict__ Lacc)
{
    const int t = threadIdx.x;
    const int lane = t & 63;
    const int wv = t >> 6;            // 0..3
    const int m = lane & 15;          // i-col / c-col / row selector
    const int q = lane >> 4;          // quad 0..3

    const int bid = blockIdx.x;
    const int s = bid & ((1 << LSPLIT) - 1);
    const int itile = (bid >> LSPLIT) & 127;
    const int b = bid >> (LSPLIT + 7);
    const int i0 = itile * 64 + wv * 16;
    const int niter = (8192 >> LSPLIT) >> 4;   // 64 tiles of 16 j
    const int jt0 = s * niter;

    const __hip_bfloat16* Kb = Kq + (size_t)b * 8192 * 16;
    const __hip_bfloat16* Vb = Vswz + (size_t)b * 262144 + lane * 4;

    // Q B-frag: B[k=4q+idx][n=m] = Kq[i0+m][4q+idx]  (8 B/lane)
    const s16x4 bq = *(const s16x4*)(Kb + (size_t)(i0 + m) * 16 + q * 4);

    floatx4 oa = {}, ob = {};         // O halves: cols 0-15 / 16-31
    float2 l01 = {0.f, 0.f};

    // prefetch it = 0
    s16x4 ak = *(const s16x4*)(Kb + (size_t)(jt0 * 16 + m) * 16 + q * 4);
    s16x4 v0 = *(const s16x4*)(Vb + (size_t)jt0 * 512 + 0);
    s16x4 v1 = *(const s16x4*)(Vb + (size_t)jt0 * 512 + 256);

    for (int it = 0; it < niter; ++it) {
        const int jtn = jt0 + (it + 1 < niter ? it + 1 : it);
        s16x4 ak_n = *(const s16x4*)(Kb + (size_t)(jtn * 16 + m) * 16 + q * 4);
        s16x4 vn0 = *(const s16x4*)(Vb + (size_t)jtn * 512 + 0);
        s16x4 vn1 = *(const s16x4*)(Vb + (size_t)jtn * 512 + 256);

        // S tile (16j x 16i) = K_rows(A) x Q_rows(B), dot-K = 16 exact.
        // S symmetric-source: D[m=4q+reg -> j][n=m -> i]
        floatx4 sc = __builtin_amdgcn_mfma_f32_16x16x16bf16_1k(ak, bq, (floatx4){}, 0, 0, 0);

        // P = 2^S ; reg r holds j_loc = 4q+r == the 16x16x16 A-layout k=4q+idx
        float e0 = __builtin_amdgcn_exp2f(sc[0]);
        float e1 = __builtin_amdgcn_exp2f(sc[1]);
        float e2 = __builtin_amdgcn_exp2f(sc[2]);
        float e3 = __builtin_amdgcn_exp2f(sc[3]);
        l01.x += e0 + e2; l01.y += e1 + e3;
#if defined(__has_builtin) && __has_builtin(__builtin_amdgcn_cvt_pk_bf16_f32)
        bf16x2 plo = __builtin_amdgcn_cvt_pk_bf16_f32(e0, e1);
        bf16x2 phi = __builtin_amdgcn_cvt_pk_bf16_f32(e2, e3);
#else
        bf16x2 plo = {(__bf16)e0, (__bf16)e1};
        bf16x2 phi = {(__bf16)e2, (__bf16)e3};
#endif
        s16x2 lo = __builtin_bit_cast(s16x2, plo);
        s16x2 hi = __builtin_bit_cast(s16x2, phi);
        s16x4 pb = {lo[0], lo[1], hi[0], hi[1]};

        // O(16i x 32c) += P(16i x 16j) x V(16j x 32c): two independent half-chains
        oa = __builtin_amdgcn_mfma_f32_16x16x16bf16_1k(pb, v0, oa, 0, 0, 0);
        ob = __builtin_amdgcn_mfma_f32_16x16x16bf16_1k(pb, v1, ob, 0, 0, 0);

        ak = ak_n; v0 = vn0; v1 = vn1;
    }

    // full row-sum of l: combine the 4 quads (lanes sharing lane&15)
    float l = l01.x + l01.y;
    l += __shfl_xor(l, 16);
    l += __shfl_xor(l, 32);

    // atomic-accumulate partials (plain sums: no max-rescaling in this scheme)
    // oa/ob reg r -> row i_loc = 4q+r, col = m (+16 for ob)
#pragma unroll
    for (int r = 0; r < 4; ++r) {
        size_t row = (size_t)b * 8192 + i0 + 4 * q + r;
        unsafeAtomicAdd(&Oacc[row * 32 + m], oa[r]);
        unsafeAtomicAdd(&Oacc[row * 32 + 16 + m], ob[r]);
    }
    if (lane < 16)
        unsafeAtomicAdd(&Lacc[(size_t)b * 8192 + i0 + m], l);
}

// ---------------- Kernel C: normalize + epilogue ----------------
__global__ __launch_bounds__(256) void finalize_kernel(
    const float* __restrict__ Oacc, const float* __restrict__ Lacc,
    const float* __restrict__ in, const float* __restrict__ gamma,
    float* __restrict__ out)
{
    const int t = threadIdx.x;
    const int c = t & 31;
    const size_t row = (size_t)blockIdx.x * 8 + (t >> 5);
    size_t idx = row * 32 + c;
    out[idx] = (Oacc[idx] / Lacc[row]) * gamma[0] + in[idx];
}

extern "C" void kernel_launch(void* const* d_in, const int* in_sizes, int n_in,
                              void* d_out, int out_size, void* d_ws, size_t ws_size,
                              hipStream_t stream) {
    const float* in = (const float*)d_in[0];
    const float* W1 = (const float*)d_in[1];
    const float* b1 = (const float*)d_in[2];
    const float* W2 = (const float*)d_in[3];
    const float* b2 = (const float*)d_in[4];
    const float* gamma = (const float*)d_in[5];
    float* out = (float*)d_out;

    __hip_bfloat16* Kq = (__hip_bfloat16*)d_ws;
    __hip_bfloat16* Vswz = Kq + KQ_ELEMS;
    float* Oacc = (float*)((char*)d_ws + OACC_OFF);
    float* Lacc = Oacc + 16384 * 32;

    proj_kernel<<<512, 256, 0, stream>>>(in, W1, b1, W2, b2, Kq, Vswz, Oacc);
    flash_kernel<<<2 * 128 * (1 << LSPLIT), 256, 0, stream>>>(Kq, Vswz, Oacc, Lacc);
    finalize_kernel<<<2048, 256, 0, stream>>>(Oacc, Lacc, in, gamma, out);
}

// Round 12
// 113.031 us; speedup vs baseline: 2.3909x; 1.1246x over previous
//
#include <hip/hip_runtime.h>
#include <hip/hip_bf16.h>
#include <math.h>

typedef __bf16 bf16x8 __attribute__((ext_vector_type(8)));
typedef __bf16 bf16x2 __attribute__((ext_vector_type(2)));
typedef short  s16x2  __attribute__((ext_vector_type(2)));
typedef short  s16x4  __attribute__((ext_vector_type(4)));
typedef float  floatx16 __attribute__((ext_vector_type(16)));

// Workspace layout (bytes):
//   Kq   bf16 [2][8192][16]   offset 0        (512 KB)  scaled by sqrt(log2 e)
//   Vswz bf16 [2][8192][32]   offset 524288   (1 MB)    32x32x8 B-frag swizzled
//   Oacc f32  [2*8192][32]    offset 1572864  (2 MB)    atomic accumulator
//   Lacc f32  [2*8192]        offset 3669888  (64 KB)
#define KQ_ELEMS (2 * 8192 * 16)
#define OACC_OFF 1572864
#define SQRT_LOG2E 1.2011224087864498f
#define LSPLIT 4

// ---------------- Kernel A: zero accumulators + projections ----------------
__global__ __launch_bounds__(256) void proj_kernel(
    const float* __restrict__ in, const float* __restrict__ W1,
    const float* __restrict__ b1, const float* __restrict__ W2,
    const float* __restrict__ b2,
    __hip_bfloat16* __restrict__ Kq, __hip_bfloat16* __restrict__ Vswz,
    float* __restrict__ acc0)
{
    __shared__ float Xs[32][32];
    __shared__ float W1s[16 * 32];
    __shared__ float W2s[32 * 32];
    const int t = threadIdx.x;
    const int bid = blockIdx.x;       // 0..511
    const int b = bid >> 8;
    const int hw = bid & 255;

    // zero accumulators: Oacc 524288 floats + Lacc 16384 floats
    {
        int gid = bid * 256 + t;                       // 0..131071
        *(float4*)(acc0 + (size_t)gid * 4) = make_float4(0.f, 0.f, 0.f, 0.f);
        if (gid < 4096)
            *(float4*)(acc0 + 524288 + (size_t)gid * 4) = make_float4(0.f, 0.f, 0.f, 0.f);
    }

    {
        int l = t >> 3, cs = (t & 7) * 4;
        float4 v = *(const float4*)(in + (((size_t)b * 32 + l) * 256 + hw) * 32 + cs);
        *(float4*)&Xs[l][cs] = v;
    }
    if (t < 128) *(float4*)&W1s[t * 4] = *(const float4*)(W1 + t * 4);
    *(float4*)&W2s[t * 4] = *(const float4*)(W2 + t * 4);
    __syncthreads();

    const int c = t & 31;
    const int g = t >> 5;             // 0..7

#pragma unroll
    for (int oo = 0; oo < 2; ++oo) {
        int o = g * 2 + oo;           // 0..15
        float acc = b1[o];
#pragma unroll
        for (int l = 0; l < 32; ++l) acc += W1s[o * 32 + l] * Xs[l][c];
        int k = c >> 1;
        int i = (c & 1) * 4096 + o * 256 + hw;
        Kq[((size_t)b * 8192 + i) * 16 + k] = __float2bfloat16(acc * SQRT_LOG2E);
    }
#pragma unroll
    for (int oo = 0; oo < 4; ++oo) {
        int o = g * 4 + oo;           // 0..31
        float acc = b2[o];
#pragma unroll
        for (int l = 0; l < 32; ++l) acc += W2s[o * 32 + l] * Xs[l][c];
        // position j = o*256 + hw, channel c; 32x32x8 B-frag swizzle:
        // flat = jt*1024 + gg*256 + h*128 + c*4 + idx
        int j = o * 256 + hw;
        int jt = j >> 5, rem = j & 31;
        int gg = rem >> 3, h = (rem >> 2) & 1, idx = rem & 3;
        Vswz[(size_t)b * 262144 + jt * 1024 + gg * 256 + h * 128 + c * 4 + idx] =
            __float2bfloat16(acc);
    }
}

// ---------------- Kernel B: flash attention, LDS-free, atomic-accumulate ----------------
// block = 256 thr (4 waves), each wave owns 32 i-rows. grid = 2 * 64 * 16 = 2048.
// NOTE: no min-waves arg in __launch_bounds__ (R7: forcing 8/EU -> VGPR 32 -> spill).
// No manual double-buffer (R12): saves ~13 live VGPRs; unroll-4 gives the
// scheduler a cross-iteration window to hoist loads instead.
__global__ __launch_bounds__(256) void flash_kernel(
    const __hip_bfloat16* __restrict__ Kq, const __hip_bfloat16* __restrict__ Vswz,
    float* __restrict__ Oacc, float* __restrict__ Lacc)
{
    const int t = threadIdx.x;
    const int lane = t & 63;
    const int wv = t >> 6;            // 0..3
    const int m = lane & 31;
    const int h = lane >> 5;          // 0/1

    const int bid = blockIdx.x;
    const int s = bid & ((1 << LSPLIT) - 1);
    const int itile = (bid >> LSPLIT) & 63;
    const int b = bid >> (LSPLIT + 6);
    const int i0 = itile * 128 + wv * 32;
    const int niter = (8192 >> LSPLIT) >> 5;   // 16 tiles of 32 j
    const int jt0 = s * niter;

    const __hip_bfloat16* Kb = Kq + (size_t)b * 8192 * 16;
    const __hip_bfloat16* Vb = Vswz + (size_t)b * 262144 + h * 128 + m * 4;

    // Q B-frag (regs): B[k=8h+idx][n=m] = Kq[i0+m][8h+idx]
    const bf16x8 bq = *(const bf16x8*)(Kb + (size_t)(i0 + m) * 16 + h * 8);

    floatx16 oa = {}, ob = {};
    float2 l01 = {0.f, 0.f}, l23 = {0.f, 0.f};

#pragma unroll 4
    for (int it = 0; it < niter; ++it) {
        const int jt = jt0 + it;
        bf16x8 ak = *(const bf16x8*)(Kb + (size_t)(jt * 32 + m) * 16 + h * 8);
        s16x4 vf0 = *(const s16x4*)(Vb + (size_t)jt * 1024 + 0);
        s16x4 vf1 = *(const s16x4*)(Vb + (size_t)jt * 1024 + 256);
        s16x4 vf2 = *(const s16x4*)(Vb + (size_t)jt * 1024 + 512);
        s16x4 vf3 = *(const s16x4*)(Vb + (size_t)jt * 1024 + 768);

        // S^T(32j x 32i) = K(A) x Q(B), K=16 exact
        floatx16 sc = __builtin_amdgcn_mfma_f32_32x32x16_bf16(ak, bq, (floatx16){}, 0, 0, 0);

        // P = 2^S ; reg 4g+idx holds j_loc = 8g+4h+idx == 32x32x8 A-layout.
#pragma unroll
        for (int g = 0; g < 4; ++g) {
            float e0 = __builtin_amdgcn_exp2f(sc[4 * g + 0]);
            float e1 = __builtin_amdgcn_exp2f(sc[4 * g + 1]);
            float e2 = __builtin_amdgcn_exp2f(sc[4 * g + 2]);
            float e3 = __builtin_amdgcn_exp2f(sc[4 * g + 3]);
            l01.x += e0; l01.y += e1; l23.x += e2; l23.y += e3;
#if defined(__has_builtin) && __has_builtin(__builtin_amdgcn_cvt_pk_bf16_f32)
            bf16x2 plo = __builtin_amdgcn_cvt_pk_bf16_f32(e0, e1);
            bf16x2 phi = __builtin_amdgcn_cvt_pk_bf16_f32(e2, e3);
#else
            bf16x2 plo = {(__bf16)e0, (__bf16)e1};
            bf16x2 phi = {(__bf16)e2, (__bf16)e3};
#endif
            s16x2 lo = __builtin_bit_cast(s16x2, plo);
            s16x2 hi = __builtin_bit_cast(s16x2, phi);
            s16x4 pb = {lo[0], lo[1], hi[0], hi[1]};
            s16x4 vf = (g == 0) ? vf0 : (g == 1) ? vf1 : (g == 2) ? vf2 : vf3;
            if (g < 2)
                oa = __builtin_amdgcn_mfma_f32_32x32x8bf16_1k(pb, vf, oa, 0, 0, 0);
            else
                ob = __builtin_amdgcn_mfma_f32_32x32x8bf16_1k(pb, vf, ob, 0, 0, 0);
        }
    }

    oa = oa + ob;
    float l = (l01.x + l01.y) + (l23.x + l23.y);
    l += __shfl_xor(l, 32);

    // atomic-accumulate partials (plain sums: no max-rescaling in this scheme)
    // reg r -> row i_loc=(r&3)+8*(r>>2)+4h, col c=m
#pragma unroll
    for (int r = 0; r < 16; ++r) {
        int iloc = (r & 3) + 8 * (r >> 2) + 4 * h;
        size_t row = (size_t)b * 8192 + i0 + iloc;
        unsafeAtomicAdd(&Oacc[row * 32 + m], oa[r]);
    }
    if (h == 0)
        unsafeAtomicAdd(&Lacc[(size_t)b * 8192 + i0 + m], l);
}

// ---------------- Kernel C: normalize + epilogue (float4 vectorized) ----------------
__global__ __launch_bounds__(256) void finalize_kernel(
    const float* __restrict__ Oacc, const float* __restrict__ Lacc,
    const float* __restrict__ in, const float* __restrict__ gamma,
    float* __restrict__ out)
{
    const int gid = blockIdx.x * 256 + threadIdx.x;   // 0..131071
    const int row = gid >> 3;
    const int c4 = (gid & 7) * 4;
    const size_t base = (size_t)row * 32 + c4;
    float4 o = *(const float4*)(Oacc + base);
    float4 x = *(const float4*)(in + base);
    const float linv = gamma[0] / Lacc[row];
    float4 r;
    r.x = o.x * linv + x.x;
    r.y = o.y * linv + x.y;
    r.z = o.z * linv + x.z;
    r.w = o.w * linv + x.w;
    *(float4*)(out + base) = r;
}

extern "C" void kernel_launch(void* const* d_in, const int* in_sizes, int n_in,
                              void* d_out, int out_size, void* d_ws, size_t ws_size,
                              hipStream_t stream) {
    const float* in = (const float*)d_in[0];
    const float* W1 = (const float*)d_in[1];
    const float* b1 = (const float*)d_in[2];
    const float* W2 = (const float*)d_in[3];
    const float* b2 = (const float*)d_in[4];
    const float* gamma = (const float*)d_in[5];
    float* out = (float*)d_out;

    __hip_bfloat16* Kq = (__hip_bfloat16*)d_ws;
    __hip_bfloat16* Vswz = Kq + KQ_ELEMS;
    float* Oacc = (float*)((char*)d_ws + OACC_OFF);
    float* Lacc = Oacc + 16384 * 32;

    proj_kernel<<<512, 256, 0, stream>>>(in, W1, b1, W2, b2, Kq, Vswz, Oacc);
    flash_kernel<<<2 * 64 * (1 << LSPLIT), 256, 0, stream>>>(Kq, Vswz, Oacc, Lacc);
    finalize_kernel<<<512, 256, 0, stream>>>(Oacc, Lacc, in, gamma, out);
}